// Round 20
// baseline (114.208 us; speedup 1.0000x reference)
//
#include <hip/hip_runtime.h>
#include <hip/hip_fp16.h>
#include <cstdint>
#include <cstddef>

#define N_Q 4096
#define M_K 16384
#define LNB 96
#define CH  512
#define NH  8

typedef _Float16 half8  __attribute__((ext_vector_type(8)));
typedef _Float16 h2     __attribute__((ext_vector_type(2)));
typedef float    floatx4 __attribute__((ext_vector_type(4)));
typedef float    floatx2 __attribute__((ext_vector_type(2)));

union H8 { half8 v; h2 p[4]; };

__device__ __forceinline__ h2 cvt2(float a, float b) {
    return __builtin_bit_cast(h2, __builtin_amdgcn_cvt_pkrtz(a, b));
}

__device__ __forceinline__ void async16(const void* g, void* l) {
    __builtin_amdgcn_global_load_lds(
        (const __attribute__((address_space(1))) void*)g,
        (__attribute__((address_space(3))) void*)l, 16, 0, 0);
}

// DPP butterfly add over an 8-lane octet (pure VALU).
template<int CTRL>
__device__ __forceinline__ float dpp_addf(float x) {
    int xi = __builtin_bit_cast(int, x);
    int yi = __builtin_amdgcn_update_dpp(xi, xi, CTRL, 0xF, 0xF, false);
    return x + __builtin_bit_cast(float, yi);
}
__device__ __forceinline__ float octet_sum(float x) {
    x = dpp_addf<0x141>(x);   // row_half_mirror
    x = dpp_addf<0x4E>(x);    // quad xor2
    x = dpp_addf<0xB1>(x);    // quad xor1
    return x;
}

// ---------------- fused weight convert: wIn (786432 f) ++ wOut (262144 f) -> fp16
__global__ void cvt_weights(const float* __restrict__ wIn, const float* __restrict__ wOut,
                            _Float16* __restrict__ dst) {
    const size_t i = (size_t)blockIdx.x * blockDim.x + threadIdx.x;   // float4 index
    const float4 v = (i < 196608) ? ((const float4*)wIn)[i]
                                  : ((const float4*)wOut)[i - 196608];
    h2 a = cvt2(v.x, v.y);
    h2 b = cvt2(v.z, v.w);
    *(h2*)&dst[i * 4]     = a;
    *(h2*)&dst[i * 4 + 2] = b;
}

// ---------------- small GEMM body (TM x 128, BK=32) -- used for out-proj --------
template<int OUTF16, int TM, int AFP32>
__device__ __forceinline__ void gemm_body(
    const void* __restrict__ Ap, const _Float16* __restrict__ Bw,
    const float* __restrict__ bias, void* __restrict__ outp, float oscale,
    int bm, int bn)
{
    constexpr int MI = TM / 32;
    __shared__ alignas(16) _Float16 As[TM * 32];
    __shared__ alignas(16) _Float16 Bs[128 * 32];

    const int t    = threadIdx.x;
    const int lane = t & 63;
    const int wave = t >> 6;
    const int wm   = wave >> 1, wn = wave & 1;

    floatx4 acc[MI][4] = {};

    const int rowL = t >> 2;
    const int kcol = (t & 3) * 8;
    const _Float16* gB = Bw + (size_t)(bn * 128 + rowL) * CH + kcol;
    _Float16* lB = &Bs[rowL * 32 + kcol];

    const _Float16* gA16 = nullptr; _Float16* lA16 = nullptr;
    const float* gA32 = nullptr; _Float16* lA32 = nullptr;
    if constexpr (AFP32) {
        gA32 = (const float*)Ap + (size_t)(bm * TM + rowL) * CH + kcol;
        lA32 = &As[rowL * 32 + kcol];
    } else {
        gA16 = (const _Float16*)Ap + (size_t)(bm * TM + rowL) * CH + kcol;
        lA16 = &As[rowL * 32 + kcol];
    }

    const int r0 = lane & 15;
    const int ko = (lane >> 4) * 8;

    for (int kt = 0; kt < CH / 32; ++kt) {
        if constexpr (AFP32) {
            const float* ga = gA32 + kt * 32;
            float4 x0 = ((const float4*)ga)[0], x1 = ((const float4*)ga)[1];
            H8 o0;
            o0.p[0] = cvt2(x0.x, x0.y);
            o0.p[1] = cvt2(x0.z, x0.w);
            o0.p[2] = cvt2(x1.x, x1.y);
            o0.p[3] = cvt2(x1.z, x1.w);
            *(half8*)lA32 = o0.v;
        } else {
            const _Float16* a0 = gA16 + kt * 32;
            async16(a0, lA16);
        }
        const _Float16* b0 = gB + kt * 32;
        async16(b0,           lB);
        async16(b0 + 64 * CH, lB + 64 * 32);
        __syncthreads();

        half8 af[MI], bf[4];
        #pragma unroll
        for (int mi = 0; mi < MI; ++mi)
            af[mi] = *(const half8*)&As[(wm * (TM / 2) + mi * 16 + r0) * 32 + ko];
        #pragma unroll
        for (int ni = 0; ni < 4; ++ni)
            bf[ni] = *(const half8*)&Bs[(wn * 64 + ni * 16 + r0) * 32 + ko];
        #pragma unroll
        for (int mi = 0; mi < MI; ++mi)
            #pragma unroll
            for (int ni = 0; ni < 4; ++ni)
                acc[mi][ni] = __builtin_amdgcn_mfma_f32_16x16x32_f16(
                    af[mi], bf[ni], acc[mi][ni], 0, 0, 0);
        __syncthreads();
    }

    #pragma unroll
    for (int mi = 0; mi < MI; ++mi) {
        #pragma unroll
        for (int ni = 0; ni < 4; ++ni) {
            const int col = bn * 128 + wn * 64 + ni * 16 + (lane & 15);
            const float bv = bias[col];
            #pragma unroll
            for (int r = 0; r < 4; ++r) {
                const int row = bm * TM + wm * (TM / 2) + mi * 16 + (lane >> 4) * 4 + r;
                const float v = (acc[mi][ni][r] + bv) * oscale;
                if (OUTF16) ((_Float16*)outp)[(size_t)row * CH + col] = (_Float16)v;
                else        ((float*)outp)[(size_t)row * CH + col]    = v;
            }
        }
    }
}

template<int OUTF16, int TM, int AFP32>
__global__ __launch_bounds__(256) void gemm_k(
    const void* __restrict__ A, const _Float16* __restrict__ Bw,
    const float* __restrict__ bias, void* __restrict__ outp, float oscale)
{
    const int bid = blockIdx.x;
    const int x   = bid & 7;
    const int i   = bid >> 3;
    const int bn  = i & 3;
    const int bm  = x + 8 * (i >> 2);
    gemm_body<OUTF16, TM, AFP32>(A, Bw, bias, outp, oscale, bm, bn);
}

// ---------------- fused QKV projection: 128 rows x FULL N=512 per block --------
// A staged ONCE (no bn duplication -> staged bytes 295MB -> 222MB, A's L3
// re-read multiplicity 4x -> 1x: the R7-R19 plateau's arithmetic).
// 512 threads = 8 waves (2M x 4N), acc[4][8] = 128 VGPR; __launch_bounds__(512,2)
// caps occupancy request so the allocator gives ~200 regs (R13's spill fix).
// BK=32, LDS 48KB (A fp32 16KB + B fp16 32KB), m97 2-barrier loop.
__global__ __launch_bounds__(512, 2) void proj_qkv(
    const float* __restrict__ query, const float* __restrict__ keyp,
    const float* __restrict__ valp, const _Float16* __restrict__ w16,
    const float* __restrict__ bIn, _Float16* __restrict__ q16,
    _Float16* __restrict__ k16, _Float16* __restrict__ v16)
{
    const int bid = blockIdx.x;
    const float* Af; const _Float16* W; const float* bias; _Float16* dst;
    float osc; int bm;

    if (bid < 128) {          // K
        bm = bid;
        Af = keyp;  W = w16 + (size_t)512 * 512;  bias = bIn + 512;  dst = k16;  osc = 1.0f;
    } else if (bid < 256) {   // V
        bm = bid - 128;
        Af = valp;  W = w16 + (size_t)1024 * 512; bias = bIn + 1024; dst = v16;  osc = 1.0f;
    } else {                  // Q
        bm = bid - 256;
        Af = query; W = w16;                      bias = bIn;        dst = q16;  osc = 0.125f;
    }

    __shared__ alignas(16) float    As[128 * 32];   // 16 KB (8 granules/row)
    __shared__ alignas(16) _Float16 Bs[512 * 32];   // 32 KB (4 granules/row)

    const char* Ab = (const char*)Af;
    const char* Bb = (const char*)W;

    const int t    = threadIdx.x;         // 0..511
    const int lane = t & 63;
    const int wv   = t >> 6;              // 0..7
    const int wm   = wv >> 2;             // 0..1
    const int wn   = wv & 3;              // 0..3
    const int r0   = lane & 15;
    const int hi   = lane >> 4;           // 0..3

    floatx4 acc[4][8] = {};

    // A: 1024 granules. LDS slot G linear; slot holds src granule (G&7)^(row&7)
    // of row G>>3. Global A row stride = 2048 B.
    uint32_t aoff[2];
    #pragma unroll
    for (int q = 0; q < 2; ++q) {
        const int G   = q * 512 + t;
        const int row = G >> 3;                   // 0..127
        const int g   = (G & 7) ^ (row & 7);
        aoff[q] = (uint32_t)((bm * 128 + row) * 2048 + g * 16);
    }
    // B: 2048 granules; row = 4 granules (64 B). Row-pair swizzle:
    // slot G holds src (row = super*2 + (sgg>>2), g = sgg&3), sgg = (G&7)^(super&7).
    // Global B row stride = 1024 B.
    uint32_t boff[4];
    #pragma unroll
    for (int q = 0; q < 4; ++q) {
        const int G     = q * 512 + t;
        const int super = G >> 3;                 // 0..255
        const int sgg   = (G & 7) ^ (super & 7);
        const int row   = super * 2 + (sgg >> 2); // 0..511
        const int g     = sgg & 3;
        boff[q] = (uint32_t)(row * 1024 + g * 16);
    }

    for (int kt = 0; kt < 16; ++kt) {
        #pragma unroll
        for (int q = 0; q < 2; ++q)
            async16(Ab + aoff[q] + kt * 128, (char*)As + (q * 512 + t) * 16);
        #pragma unroll
        for (int q = 0; q < 4; ++q)
            async16(Bb + boff[q] + kt * 64,  (char*)Bs + (q * 512 + t) * 16);
        __syncthreads();

        half8 af[4], bf[8];
        #pragma unroll
        for (int mi = 0; mi < 4; ++mi) {
            const int row = wm * 64 + mi * 16 + r0;     // 0..127
            const int swz = row & 7;
            const float4 x0 = *(const float4*)((const char*)As + row * 128 + (((hi * 2)     ^ swz) * 16));
            const float4 x1 = *(const float4*)((const char*)As + row * 128 + (((hi * 2 + 1) ^ swz) * 16));
            H8 o;
            o.p[0] = cvt2(x0.x, x0.y);
            o.p[1] = cvt2(x0.z, x0.w);
            o.p[2] = cvt2(x1.x, x1.y);
            o.p[3] = cvt2(x1.z, x1.w);
            af[mi] = o.v;
        }
        #pragma unroll
        for (int ni = 0; ni < 8; ++ni) {
            const int row   = wn * 128 + ni * 16 + r0;  // 0..511
            const int super = row >> 1;
            const int vv    = ((row & 1) * 4 + hi) ^ (super & 7);
            bf[ni] = *(const half8*)((const char*)Bs + super * 128 + vv * 16);
        }
        #pragma unroll
        for (int mi = 0; mi < 4; ++mi)
            #pragma unroll
            for (int ni = 0; ni < 8; ++ni)
                acc[mi][ni] = __builtin_amdgcn_mfma_f32_16x16x32_f16(
                    af[mi], bf[ni], acc[mi][ni], 0, 0, 0);
        __syncthreads();
    }

    #pragma unroll
    for (int mi = 0; mi < 4; ++mi) {
        #pragma unroll
        for (int ni = 0; ni < 8; ++ni) {
            const int col = wn * 128 + ni * 16 + r0;
            const float bv = bias[col];
            #pragma unroll
            for (int r = 0; r < 4; ++r) {
                const int row = bm * 128 + wm * 64 + mi * 16 + hi * 4 + r;
                dst[(size_t)row * CH + col] = (_Float16)((acc[mi][ni][r] + bv) * osc);
            }
        }
    }
}

// ---------------- local attention: one block (256 thr) per query ----------------
__global__ __launch_bounds__(256) void attn_kernel(
    const _Float16* __restrict__ q16, const _Float16* __restrict__ k16,
    const _Float16* __restrict__ v16, const int* __restrict__ ipair,
    const int* __restrict__ ibatch, const int* __restrict__ kcnt,
    _Float16* __restrict__ op16, float* __restrict__ aout)
{
    __shared__ uint32_t vmask[LNB];       // row byte-offset | (masked<<31)
    __shared__ float    pls[LNB * 9];     // logits -> probs (stride 9)
    __shared__ __half2  pph[LNB * 9];     // probs pre-packed {p,p} fp16
    __shared__ float    part[4][CH];      // per-wave PV partials

    const int t = threadIdx.x;
    // XCD swizzle: batch b = n/512 -> XCD b (one batch's K+V fp16 fits one L2)
    const int n = ((blockIdx.x & 7) << 9) | (blockIdx.x >> 3);

    if (t < LNB) {
        const int idx = ipair[(size_t)n * LNB + t];
        const int b   = ibatch[n];
        int off = 0;
        for (int i = 0; i < b; ++i) off += kcnt[i];
        const uint32_t vo = (uint32_t)((idx < 0 ? 0 : (idx + off)) * (CH * 2));
        vmask[t] = vo | (idx < 0 ? 0x80000000u : 0u);
    }
    __syncthreads();

    const int lane = t & 63, wv = t >> 6;
    const int h    = lane >> 3;           // head for this lane
    const int l0   = wv * 24;             // wave's contiguous l-chunk

    // ---- phase 1: logits. lane owns dims [lane*8, +8); octet = one head.
    {
        const half8 qv = *(const half8*)(q16 + (size_t)n * CH + lane * 8);
        H8 qu; qu.v = qv;
        const char* kbase = (const char*)k16 + lane * 16;
        const int4* vb = (const int4*)&vmask[l0];
        for (int g = 0; g < 3; ++g) {
            const int4 w0 = vb[2 * g], w1 = vb[2 * g + 1];
            uint32_t vm8[8] = {(uint32_t)w0.x, (uint32_t)w0.y, (uint32_t)w0.z, (uint32_t)w0.w,
                               (uint32_t)w1.x, (uint32_t)w1.y, (uint32_t)w1.z, (uint32_t)w1.w};
            #pragma unroll
            for (int j = 0; j < 8; ++j) {
                const uint32_t vms = __builtin_amdgcn_readfirstlane(vm8[j]);
                H8 ku; ku.v = *(const half8*)(kbase + (vms & 0x7fffffffu));
                float acc = 0.f;
                #pragma unroll
                for (int u = 0; u < 4; ++u)
                    acc = __builtin_amdgcn_fdot2(qu.p[u], ku.p[u], acc, false);
                acc = octet_sum(acc);
                if ((lane & 7) == 0)
                    pls[(l0 + g * 8 + j) * 9 + h] = (vms & 0x80000000u) ? -1e30f : acc;
            }
        }
    }
    __syncthreads();

    // ---- phase 2: softmax over L per head (hh = t>>5, j = t&31)
    {
        const int hh = t >> 5, j = t & 31;
        const float v0 = pls[j * 9 + hh];
        const float v1 = pls[(j + 32) * 9 + hh];
        const float v2 = pls[(j + 64) * 9 + hh];
        float m = fmaxf(v0, fmaxf(v1, v2));
        #pragma unroll
        for (int s = 16; s >= 1; s >>= 1) m = fmaxf(m, __shfl_xor(m, s, 32));
        const float e0 = __expf(v0 - m), e1 = __expf(v1 - m), e2 = __expf(v2 - m);
        float ssum = e0 + e1 + e2;
        #pragma unroll
        for (int s = 16; s >= 1; s >>= 1) ssum += __shfl_xor(ssum, s, 32);
        const float rinv = 1.0f / ssum;
        const float p0 = e0 * rinv, p1 = e1 * rinv, p2 = e2 * rinv;
        pls[j * 9 + hh]        = p0;
        pls[(j + 32) * 9 + hh] = p1;
        pls[(j + 64) * 9 + hh] = p2;
        pph[j * 9 + hh]        = __half2half2(__float2half_rn(p0));
        pph[(j + 32) * 9 + hh] = __half2half2(__float2half_rn(p1));
        pph[(j + 64) * 9 + hh] = __half2half2(__float2half_rn(p2));
    }
    __syncthreads();

    // ---- attn_mean (output 1)
    if (t < LNB) {
        float s = 0.f;
        #pragma unroll
        for (int u = 0; u < NH; ++u) s += pls[t * 9 + u];
        aout[(size_t)n * LNB + t] = s * (1.0f / NH);
    }

    // ---- phase 3: PV. wave owns l in [l0, l0+24), lane owns 8 dims.
    {
        float accf[8] = {};
        const char* vbase = (const char*)v16 + lane * 16;
        const int4* vb = (const int4*)&vmask[l0];
        const __half2 hz = __half2half2(__float2half_rn(0.f));
        for (int g = 0; g < 3; ++g) {
            const int4 w0 = vb[2 * g], w1 = vb[2 * g + 1];
            uint32_t vm8[8] = {(uint32_t)w0.x, (uint32_t)w0.y, (uint32_t)w0.z, (uint32_t)w0.w,
                               (uint32_t)w1.x, (uint32_t)w1.y, (uint32_t)w1.z, (uint32_t)w1.w};
            __half2 a0 = hz, a1 = hz, a2 = hz, a3 = hz;
            #pragma unroll
            for (int j = 0; j < 8; ++j) {
                const uint32_t vms = __builtin_amdgcn_readfirstlane(vm8[j]);
                const half8 vv = *(const half8*)(vbase + (vms & 0x7fffffffu));
                union { half8 v; __half2 q[4]; } vu; vu.v = vv;
                const __half2 pp = pph[(l0 + g * 8 + j) * 9 + h];
                a0 = __hfma2(pp, vu.q[0], a0);
                a1 = __hfma2(pp, vu.q[1], a1);
                a2 = __hfma2(pp, vu.q[2], a2);
                a3 = __hfma2(pp, vu.q[3], a3);
            }
            float2 f;
            f = __half22float2(a0); accf[0] += f.x; accf[1] += f.y;
            f = __half22float2(a1); accf[2] += f.x; accf[3] += f.y;
            f = __half22float2(a2); accf[4] += f.x; accf[5] += f.y;
            f = __half22float2(a3); accf[6] += f.x; accf[7] += f.y;
        }
        floatx4 lo, hi;
        #pragma unroll
        for (int u = 0; u < 4; ++u) { lo[u] = accf[u]; hi[u] = accf[u + 4]; }
        *(floatx4*)&part[wv][lane * 8]     = lo;
        *(floatx4*)&part[wv][lane * 8 + 4] = hi;
    }
    __syncthreads();

    // ---- final cross-wave reduce: thread t owns dims 2t, 2t+1
    {
        const int c = t * 2;
        floatx2 s = *(const floatx2*)&part[0][c];
        #pragma unroll
        for (int w = 1; w < 4; ++w) {
            floatx2 pw = *(const floatx2*)&part[w][c];
            s[0] += pw[0]; s[1] += pw[1];
        }
        h2 o; o[0] = (_Float16)s[0]; o[1] = (_Float16)s[1];
        *(h2*)&op16[(size_t)n * CH + c] = o;
    }
}

extern "C" void kernel_launch(void* const* d_in, const int* in_sizes, int n_in,
                              void* d_out, int out_size, void* d_ws, size_t ws_size,
                              hipStream_t stream)
{
    const float* query = (const float*)d_in[0];
    const float* key   = (const float*)d_in[1];
    const float* value = (const float*)d_in[2];
    const int*   ipair = (const int*)d_in[3];
    const int*   kcnt  = (const int*)d_in[5];
    const int*   ibat  = (const int*)d_in[6];
    const float* wIn   = (const float*)d_in[7];
    const float* bIn   = (const float*)d_in[8];
    const float* wOut  = (const float*)d_in[9];
    const float* bOut  = (const float*)d_in[10];

    float* out  = (float*)d_out;
    float* aout = out + (size_t)N_Q * CH;

    char* ws = (char*)d_ws;
    _Float16* w16  = (_Float16*)(ws);                // in-proj weights fp16 (1.5MB)
    _Float16* wo16 = (_Float16*)(ws + 1572864);      // out-proj weights fp16 (contiguous)
    _Float16* q16  = (_Float16*)(ws + 2097152);      // 4MB
    _Float16* k16  = (_Float16*)(ws + 6291456);      // 16MB
    _Float16* v16  = (_Float16*)(ws + 23068672);     // 16MB
    _Float16* op16 = (_Float16*)(ws + 39845888);     // 4MB

    // one fused weight convert (wIn ++ wOut -> w16 ++ wo16)
    cvt_weights<<<1024, 256, 0, stream>>>(wIn, wOut, w16);

    // fused Q+K+V projection: full-width 128x512 blocks, A staged ONCE
    proj_qkv<<<288, 512, 0, stream>>>(query, key, value, w16, bIn, q16, k16, v16);

    attn_kernel<<<4096, 256, 0, stream>>>(q16, k16, v16, ipair, ibat, kcnt, op16, aout);

    // out projection (fp16 A), proven 64-tile body
    gemm_k<0, 64, 0><<<256, 256, 0, stream>>>(op16, wo16, bOut, d_out, 1.0f);
}

// Round 21
// 91.640 us; speedup vs baseline: 1.2463x; 1.2463x over previous
//
#include <hip/hip_runtime.h>
#include <hip/hip_fp16.h>
#include <cstdint>
#include <cstddef>

#define N_Q 4096
#define M_K 16384
#define LNB 96
#define CH  512
#define NH  8

typedef _Float16 half8  __attribute__((ext_vector_type(8)));
typedef _Float16 h2     __attribute__((ext_vector_type(2)));
typedef float    floatx4 __attribute__((ext_vector_type(4)));
typedef float    floatx2 __attribute__((ext_vector_type(2)));

union H8 { half8 v; h2 p[4]; };

__device__ __forceinline__ h2 cvt2(float a, float b) {
    return __builtin_bit_cast(h2, __builtin_amdgcn_cvt_pkrtz(a, b));
}

__device__ __forceinline__ void async16(const void* g, void* l) {
    __builtin_amdgcn_global_load_lds(
        (const __attribute__((address_space(1))) void*)g,
        (__attribute__((address_space(3))) void*)l, 16, 0, 0);
}

// DPP butterfly add over an 8-lane octet (pure VALU).
template<int CTRL>
__device__ __forceinline__ float dpp_addf(float x) {
    int xi = __builtin_bit_cast(int, x);
    int yi = __builtin_amdgcn_update_dpp(xi, xi, CTRL, 0xF, 0xF, false);
    return x + __builtin_bit_cast(float, yi);
}
__device__ __forceinline__ float octet_sum(float x) {
    x = dpp_addf<0x141>(x);   // row_half_mirror
    x = dpp_addf<0x4E>(x);    // quad xor2
    x = dpp_addf<0xB1>(x);    // quad xor1
    return x;
}

// ---------------- fused weight convert: wIn (786432 f) ++ wOut (262144 f) -> fp16
__global__ void cvt_weights(const float* __restrict__ wIn, const float* __restrict__ wOut,
                            _Float16* __restrict__ dst) {
    const size_t i = (size_t)blockIdx.x * blockDim.x + threadIdx.x;   // float4 index
    const float4 v = (i < 196608) ? ((const float4*)wIn)[i]
                                  : ((const float4*)wOut)[i - 196608];
    h2 a = cvt2(v.x, v.y);
    h2 b = cvt2(v.z, v.w);
    *(h2*)&dst[i * 4]     = a;
    *(h2*)&dst[i * 4 + 2] = b;
}

// ---------------- small GEMM body (TM x 128, BK=32) -- used for out-proj --------
template<int OUTF16, int TM, int AFP32>
__device__ __forceinline__ void gemm_body(
    const void* __restrict__ Ap, const _Float16* __restrict__ Bw,
    const float* __restrict__ bias, void* __restrict__ outp, float oscale,
    int bm, int bn)
{
    constexpr int MI = TM / 32;
    __shared__ alignas(16) _Float16 As[TM * 32];
    __shared__ alignas(16) _Float16 Bs[128 * 32];

    const int t    = threadIdx.x;
    const int lane = t & 63;
    const int wave = t >> 6;
    const int wm   = wave >> 1, wn = wave & 1;

    floatx4 acc[MI][4] = {};

    const int rowL = t >> 2;
    const int kcol = (t & 3) * 8;
    const _Float16* gB = Bw + (size_t)(bn * 128 + rowL) * CH + kcol;
    _Float16* lB = &Bs[rowL * 32 + kcol];

    const _Float16* gA16 = nullptr; _Float16* lA16 = nullptr;
    const float* gA32 = nullptr; _Float16* lA32 = nullptr;
    if constexpr (AFP32) {
        gA32 = (const float*)Ap + (size_t)(bm * TM + rowL) * CH + kcol;
        lA32 = &As[rowL * 32 + kcol];
    } else {
        gA16 = (const _Float16*)Ap + (size_t)(bm * TM + rowL) * CH + kcol;
        lA16 = &As[rowL * 32 + kcol];
    }

    const int r0 = lane & 15;
    const int ko = (lane >> 4) * 8;

    for (int kt = 0; kt < CH / 32; ++kt) {
        if constexpr (AFP32) {
            const float* ga = gA32 + kt * 32;
            float4 x0 = ((const float4*)ga)[0], x1 = ((const float4*)ga)[1];
            H8 o0;
            o0.p[0] = cvt2(x0.x, x0.y);
            o0.p[1] = cvt2(x0.z, x0.w);
            o0.p[2] = cvt2(x1.x, x1.y);
            o0.p[3] = cvt2(x1.z, x1.w);
            *(half8*)lA32 = o0.v;
        } else {
            const _Float16* a0 = gA16 + kt * 32;
            async16(a0, lA16);
        }
        const _Float16* b0 = gB + kt * 32;
        async16(b0,           lB);
        async16(b0 + 64 * CH, lB + 64 * 32);
        __syncthreads();

        half8 af[MI], bf[4];
        #pragma unroll
        for (int mi = 0; mi < MI; ++mi)
            af[mi] = *(const half8*)&As[(wm * (TM / 2) + mi * 16 + r0) * 32 + ko];
        #pragma unroll
        for (int ni = 0; ni < 4; ++ni)
            bf[ni] = *(const half8*)&Bs[(wn * 64 + ni * 16 + r0) * 32 + ko];
        #pragma unroll
        for (int mi = 0; mi < MI; ++mi)
            #pragma unroll
            for (int ni = 0; ni < 4; ++ni)
                acc[mi][ni] = __builtin_amdgcn_mfma_f32_16x16x32_f16(
                    af[mi], bf[ni], acc[mi][ni], 0, 0, 0);
        __syncthreads();
    }

    #pragma unroll
    for (int mi = 0; mi < MI; ++mi) {
        #pragma unroll
        for (int ni = 0; ni < 4; ++ni) {
            const int col = bn * 128 + wn * 64 + ni * 16 + (lane & 15);
            const float bv = bias[col];
            #pragma unroll
            for (int r = 0; r < 4; ++r) {
                const int row = bm * TM + wm * (TM / 2) + mi * 16 + (lane >> 4) * 4 + r;
                const float v = (acc[mi][ni][r] + bv) * oscale;
                if (OUTF16) ((_Float16*)outp)[(size_t)row * CH + col] = (_Float16)v;
                else        ((float*)outp)[(size_t)row * CH + col]    = v;
            }
        }
    }
}

template<int OUTF16, int TM, int AFP32>
__global__ __launch_bounds__(256) void gemm_k(
    const void* __restrict__ A, const _Float16* __restrict__ Bw,
    const float* __restrict__ bias, void* __restrict__ outp, float oscale)
{
    const int bid = blockIdx.x;
    const int x   = bid & 7;
    const int i   = bid >> 3;
    const int bn  = i & 3;
    const int bm  = x + 8 * (i >> 2);
    gemm_body<OUTF16, TM, AFP32>(A, Bw, bias, outp, oscale, bm, bn);
}

// ---------------- fused QKV projection: 128(M) x 256(N), BK=64, 512 threads ----
// Best-known config (R19, 91.96 us total). 8 K-steps x 32 MFMA, LDS 64KB,
// 2 blocks/CU, rule-#21 swizzles, XCD grouping.
__global__ __launch_bounds__(512, 4) void proj_qkv(
    const float* __restrict__ query, const float* __restrict__ keyp,
    const float* __restrict__ valp, const _Float16* __restrict__ w16,
    const float* __restrict__ bIn, _Float16* __restrict__ q16,
    _Float16* __restrict__ k16, _Float16* __restrict__ v16)
{
    const int bid = blockIdx.x;
    const float* Af; const _Float16* W; const float* bias; _Float16* dst;
    float osc; int bm, cb;

    if (bid < 512) {
        // K/V: bn 0..3 -> [K:0-255, K:256-511, V:0-255, V:256-511], XCD-grouped
        const int x = bid & 7;
        const int i = bid >> 3;
        const int bn = i & 3;
        bm = x + 8 * (i >> 2);            // 0..127
        const int z = bn >> 1;
        cb = (bn & 1) * 256;
        Af   = z ? valp : keyp;
        W    = w16 + (size_t)(512 + bn * 256) * 512;
        bias = bIn + 512 + bn * 256;
        dst  = z ? v16 : k16;
        osc  = 1.0f;
    } else {
        // Q: 64 blocks (32 bm x 2 bn)
        const int j = bid - 512;
        const int x = j & 7;
        const int jj = j >> 3;            // 0..7
        const int bn = jj & 1;
        bm = x + 8 * (jj >> 1);           // 0..31
        cb = bn * 256;
        Af   = query;
        W    = w16 + (size_t)(bn * 256) * 512;
        bias = bIn + bn * 256;
        dst  = q16;
        osc  = 0.125f;
    }

    __shared__ alignas(16) float    As[128 * 64];   // 32 KB, LDS row = 16 granules
    __shared__ alignas(16) _Float16 Bs[256 * 64];   // 32 KB, LDS row = 8 granules

    const char* Ab = (const char*)Af;
    const char* Bb = (const char*)W;

    const int t    = threadIdx.x;        // 0..511
    const int lane = t & 63;
    const int wv   = t >> 6;             // 0..7
    const int wm   = wv >> 2;            // 0..1
    const int wn   = wv & 3;             // 0..3
    const int r0   = lane & 15;
    const int hi   = lane >> 4;          // 0..3
    const int sw2  = (r0 & 7) << 1;      // A read swizzle (row&7)<<1

    floatx4 acc[4][4] = {};

    // A: 2048 granules (16B). LDS slot G linear; slot holds src granule
    // (G&15)^((row&7)<<1) of row G>>4.  Global A row stride = CH*4 = 2048 B.
    uint32_t aoff[4];
    #pragma unroll
    for (int q = 0; q < 4; ++q) {
        const int G    = q * 512 + t;
        const int row  = G >> 4;
        const int srcg = (G & 15) ^ ((row & 7) << 1);
        aoff[q] = (uint32_t)((bm * 128 + row) * 2048 + srcg * 16);
    }
    // B: 2048 granules; slot holds src granule (G&7)^(row&7) of row G>>3.
    // Global B row stride = CH*2 = 1024 B.
    uint32_t boff[4];
    #pragma unroll
    for (int q = 0; q < 4; ++q) {
        const int G    = q * 512 + t;
        const int row  = G >> 3;
        const int srcg = (G & 7) ^ (row & 7);
        boff[q] = (uint32_t)(row * 1024 + srcg * 16);
    }

    for (int kt = 0; kt < 8; ++kt) {
        #pragma unroll
        for (int q = 0; q < 4; ++q)
            async16(Ab + aoff[q] + kt * 256, (char*)As + (q * 512 + t) * 16);
        #pragma unroll
        for (int q = 0; q < 4; ++q)
            async16(Bb + boff[q] + kt * 128, (char*)Bs + (q * 512 + t) * 16);
        __syncthreads();

        #pragma unroll
        for (int kh = 0; kh < 2; ++kh) {
            half8 af[4], bf[4];
            #pragma unroll
            for (int mi = 0; mi < 4; ++mi) {
                const int row   = wm * 64 + mi * 16 + r0;   // row&7 == r0&7
                const int slot0 = (kh * 8 + hi * 2)     ^ sw2;
                const int slot1 = (kh * 8 + hi * 2 + 1) ^ sw2;
                const float4 x0 = *(const float4*)((const char*)As + row * 256 + slot0 * 16);
                const float4 x1 = *(const float4*)((const char*)As + row * 256 + slot1 * 16);
                H8 o;
                o.p[0] = cvt2(x0.x, x0.y);
                o.p[1] = cvt2(x0.z, x0.w);
                o.p[2] = cvt2(x1.x, x1.y);
                o.p[3] = cvt2(x1.z, x1.w);
                af[mi] = o.v;
            }
            #pragma unroll
            for (int ni = 0; ni < 4; ++ni) {
                const int row  = wn * 64 + ni * 16 + r0;    // 0..255
                const int slot = (kh * 4 + hi) ^ (row & 7);
                bf[ni] = *(const half8*)((const char*)Bs + row * 128 + slot * 16);
            }
            #pragma unroll
            for (int mi = 0; mi < 4; ++mi)
                #pragma unroll
                for (int ni = 0; ni < 4; ++ni)
                    acc[mi][ni] = __builtin_amdgcn_mfma_f32_16x16x32_f16(
                        af[mi], bf[ni], acc[mi][ni], 0, 0, 0);
        }
        __syncthreads();
    }

    #pragma unroll
    for (int mi = 0; mi < 4; ++mi) {
        #pragma unroll
        for (int ni = 0; ni < 4; ++ni) {
            const int lc  = wn * 64 + ni * 16 + r0;
            const int col = cb + lc;
            const float bv = bias[lc];
            #pragma unroll
            for (int r = 0; r < 4; ++r) {
                const int row = bm * 128 + wm * 64 + mi * 16 + hi * 4 + r;
                dst[(size_t)row * CH + col] = (_Float16)((acc[mi][ni][r] + bv) * osc);
            }
        }
    }
}

// ---------------- local attention: one block (256 thr) per query ----------------
__global__ __launch_bounds__(256) void attn_kernel(
    const _Float16* __restrict__ q16, const _Float16* __restrict__ k16,
    const _Float16* __restrict__ v16, const int* __restrict__ ipair,
    const int* __restrict__ ibatch, const int* __restrict__ kcnt,
    _Float16* __restrict__ op16, float* __restrict__ aout)
{
    __shared__ uint32_t vmask[LNB];       // row byte-offset | (masked<<31)
    __shared__ float    pls[LNB * 9];     // logits -> probs (stride 9)
    __shared__ __half2  pph[LNB * 9];     // probs pre-packed {p,p} fp16
    __shared__ float    part[4][CH];      // per-wave PV partials

    const int t = threadIdx.x;
    // XCD swizzle: batch b = n/512 -> XCD b (one batch's K+V fp16 fits one L2)
    const int n = ((blockIdx.x & 7) << 9) | (blockIdx.x >> 3);

    if (t < LNB) {
        const int idx = ipair[(size_t)n * LNB + t];
        const int b   = ibatch[n];
        int off = 0;
        for (int i = 0; i < b; ++i) off += kcnt[i];
        const uint32_t vo = (uint32_t)((idx < 0 ? 0 : (idx + off)) * (CH * 2));
        vmask[t] = vo | (idx < 0 ? 0x80000000u : 0u);
    }
    __syncthreads();

    const int lane = t & 63, wv = t >> 6;
    const int h    = lane >> 3;           // head for this lane
    const int l0   = wv * 24;             // wave's contiguous l-chunk

    // ---- phase 1: logits. lane owns dims [lane*8, +8); octet = one head.
    {
        const half8 qv = *(const half8*)(q16 + (size_t)n * CH + lane * 8);
        H8 qu; qu.v = qv;
        const char* kbase = (const char*)k16 + lane * 16;
        const int4* vb = (const int4*)&vmask[l0];
        for (int g = 0; g < 3; ++g) {
            const int4 w0 = vb[2 * g], w1 = vb[2 * g + 1];
            uint32_t vm8[8] = {(uint32_t)w0.x, (uint32_t)w0.y, (uint32_t)w0.z, (uint32_t)w0.w,
                               (uint32_t)w1.x, (uint32_t)w1.y, (uint32_t)w1.z, (uint32_t)w1.w};
            #pragma unroll
            for (int j = 0; j < 8; ++j) {
                const uint32_t vms = __builtin_amdgcn_readfirstlane(vm8[j]);
                H8 ku; ku.v = *(const half8*)(kbase + (vms & 0x7fffffffu));
                float acc = 0.f;
                #pragma unroll
                for (int u = 0; u < 4; ++u)
                    acc = __builtin_amdgcn_fdot2(qu.p[u], ku.p[u], acc, false);
                acc = octet_sum(acc);
                if ((lane & 7) == 0)
                    pls[(l0 + g * 8 + j) * 9 + h] = (vms & 0x80000000u) ? -1e30f : acc;
            }
        }
    }
    __syncthreads();

    // ---- phase 2: softmax over L per head (hh = t>>5, j = t&31)
    {
        const int hh = t >> 5, j = t & 31;
        const float v0 = pls[j * 9 + hh];
        const float v1 = pls[(j + 32) * 9 + hh];
        const float v2 = pls[(j + 64) * 9 + hh];
        float m = fmaxf(v0, fmaxf(v1, v2));
        #pragma unroll
        for (int s = 16; s >= 1; s >>= 1) m = fmaxf(m, __shfl_xor(m, s, 32));
        const float e0 = __expf(v0 - m), e1 = __expf(v1 - m), e2 = __expf(v2 - m);
        float ssum = e0 + e1 + e2;
        #pragma unroll
        for (int s = 16; s >= 1; s >>= 1) ssum += __shfl_xor(ssum, s, 32);
        const float rinv = 1.0f / ssum;
        const float p0 = e0 * rinv, p1 = e1 * rinv, p2 = e2 * rinv;
        pls[j * 9 + hh]        = p0;
        pls[(j + 32) * 9 + hh] = p1;
        pls[(j + 64) * 9 + hh] = p2;
        pph[j * 9 + hh]        = __half2half2(__float2half_rn(p0));
        pph[(j + 32) * 9 + hh] = __half2half2(__float2half_rn(p1));
        pph[(j + 64) * 9 + hh] = __half2half2(__float2half_rn(p2));
    }
    __syncthreads();

    // ---- attn_mean (output 1)
    if (t < LNB) {
        float s = 0.f;
        #pragma unroll
        for (int u = 0; u < NH; ++u) s += pls[t * 9 + u];
        aout[(size_t)n * LNB + t] = s * (1.0f / NH);
    }

    // ---- phase 3: PV. wave owns l in [l0, l0+24), lane owns 8 dims.
    {
        float accf[8] = {};
        const char* vbase = (const char*)v16 + lane * 16;
        const int4* vb = (const int4*)&vmask[l0];
        const __half2 hz = __half2half2(__float2half_rn(0.f));
        for (int g = 0; g < 3; ++g) {
            const int4 w0 = vb[2 * g], w1 = vb[2 * g + 1];
            uint32_t vm8[8] = {(uint32_t)w0.x, (uint32_t)w0.y, (uint32_t)w0.z, (uint32_t)w0.w,
                               (uint32_t)w1.x, (uint32_t)w1.y, (uint32_t)w1.z, (uint32_t)w1.w};
            __half2 a0 = hz, a1 = hz, a2 = hz, a3 = hz;
            #pragma unroll
            for (int j = 0; j < 8; ++j) {
                const uint32_t vms = __builtin_amdgcn_readfirstlane(vm8[j]);
                const half8 vv = *(const half8*)(vbase + (vms & 0x7fffffffu));
                union { half8 v; __half2 q[4]; } vu; vu.v = vv;
                const __half2 pp = pph[(l0 + g * 8 + j) * 9 + h];
                a0 = __hfma2(pp, vu.q[0], a0);
                a1 = __hfma2(pp, vu.q[1], a1);
                a2 = __hfma2(pp, vu.q[2], a2);
                a3 = __hfma2(pp, vu.q[3], a3);
            }
            float2 f;
            f = __half22float2(a0); accf[0] += f.x; accf[1] += f.y;
            f = __half22float2(a1); accf[2] += f.x; accf[3] += f.y;
            f = __half22float2(a2); accf[4] += f.x; accf[5] += f.y;
            f = __half22float2(a3); accf[6] += f.x; accf[7] += f.y;
        }
        floatx4 lo, hi;
        #pragma unroll
        for (int u = 0; u < 4; ++u) { lo[u] = accf[u]; hi[u] = accf[u + 4]; }
        *(floatx4*)&part[wv][lane * 8]     = lo;
        *(floatx4*)&part[wv][lane * 8 + 4] = hi;
    }
    __syncthreads();

    // ---- final cross-wave reduce: thread t owns dims 2t, 2t+1
    {
        const int c = t * 2;
        floatx2 s = *(const floatx2*)&part[0][c];
        #pragma unroll
        for (int w = 1; w < 4; ++w) {
            floatx2 pw = *(const floatx2*)&part[w][c];
            s[0] += pw[0]; s[1] += pw[1];
        }
        h2 o; o[0] = (_Float16)s[0]; o[1] = (_Float16)s[1];
        *(h2*)&op16[(size_t)n * CH + c] = o;
    }
}

extern "C" void kernel_launch(void* const* d_in, const int* in_sizes, int n_in,
                              void* d_out, int out_size, void* d_ws, size_t ws_size,
                              hipStream_t stream)
{
    const float* query = (const float*)d_in[0];
    const float* key   = (const float*)d_in[1];
    const float* value = (const float*)d_in[2];
    const int*   ipair = (const int*)d_in[3];
    const int*   kcnt  = (const int*)d_in[5];
    const int*   ibat  = (const int*)d_in[6];
    const float* wIn   = (const float*)d_in[7];
    const float* bIn   = (const float*)d_in[8];
    const float* wOut  = (const float*)d_in[9];
    const float* bOut  = (const float*)d_in[10];

    float* out  = (float*)d_out;
    float* aout = out + (size_t)N_Q * CH;

    char* ws = (char*)d_ws;
    _Float16* w16  = (_Float16*)(ws);                // in-proj weights fp16 (1.5MB)
    _Float16* wo16 = (_Float16*)(ws + 1572864);      // out-proj weights fp16 (contiguous)
    _Float16* q16  = (_Float16*)(ws + 2097152);      // 4MB
    _Float16* k16  = (_Float16*)(ws + 6291456);      // 16MB
    _Float16* v16  = (_Float16*)(ws + 23068672);     // 16MB
    _Float16* op16 = (_Float16*)(ws + 39845888);     // 4MB

    // one fused weight convert (wIn ++ wOut -> w16 ++ wo16)
    cvt_weights<<<1024, 256, 0, stream>>>(wIn, wOut, w16);

    // fused Q+K+V projection: 128x256 tiles, BK=64 (8 steps), XCD-grouped
    proj_qkv<<<576, 512, 0, stream>>>(query, key, value, w16, bIn, q16, k16, v16);

    attn_kernel<<<4096, 256, 0, stream>>>(q16, k16, v16, ipair, ibat, kcnt, op16, aout);

    // out projection (fp16 A), proven 64-tile body
    gemm_k<0, 64, 0><<<256, 256, 0, stream>>>(op16, wo16, bOut, d_out, 1.0f);
}